// Round 1
// baseline (4406.848 us; speedup 1.0000x reference)
//
#include <hip/hip_runtime.h>

// LSTM T=256, B=128, D=512, H=512.
// Strategy: bf16 MFMA (16x16x32) persistent kernel, one grid barrier per timestep.
//   ws layout: Xbf [T*B*D bf16]=32MB | WT [2048x1024 bf16]=4MB | hbuf [2][B][H] bf16 | flags
//   A = [x_t | h_{t-1}] (128 x 1024), B = WT^T rows (gate-major: g = q*512 + j), K = 1024.
//   64 blocks (4 row-blocks x 16 hidden-blocks), 256 threads (4 waves).
//   Block tile: 32 batch rows x 32 hidden units (= 128 gate columns).
//   Wave (rt=wave>>1, ch=wave&1): 16 rows x 16 hidden, computes all 4 gates -> in-register
//   gate combine using C/D layout col=lane&15, row=(lane>>4)*4+r.

#define TT 256
#define BB 128
#define DD 512
#define HH 512
#define KK 1024
#define NBLK 64

typedef __bf16 bf16x8 __attribute__((ext_vector_type(8)));
typedef float f32x4 __attribute__((ext_vector_type(4)));
typedef unsigned short u16x8 __attribute__((ext_vector_type(8)));

__device__ __forceinline__ unsigned short f2bf(float f) {
  unsigned b = __builtin_bit_cast(unsigned, f);
  return (unsigned short)((b + 0x7fffu + ((b >> 16) & 1u)) >> 16);
}

__device__ __forceinline__ float fexp(float x) {
  return __builtin_amdgcn_exp2f(x * 1.4426950408889634f);
}
__device__ __forceinline__ float fsig(float x) {
  return __builtin_amdgcn_rcpf(1.0f + fexp(-x));
}
__device__ __forceinline__ float ftanh(float x) {
  return 2.0f * fsig(2.0f * x) - 1.0f;
}

// ---- prep: X fp32 -> bf16 (RNE), 8 elems/thread ----
__global__ __launch_bounds__(256) void convert_x_kernel(const float* __restrict__ X,
                                                        unsigned short* __restrict__ Xbf) {
  size_t i = (size_t)blockIdx.x * 256 + threadIdx.x;
  const float4* src = (const float4*)X + i * 2;
  float4 v0 = src[0], v1 = src[1];
  u16x8 o;
  o[0] = f2bf(v0.x); o[1] = f2bf(v0.y); o[2] = f2bf(v0.z); o[3] = f2bf(v0.w);
  o[4] = f2bf(v1.x); o[5] = f2bf(v1.y); o[6] = f2bf(v1.z); o[7] = f2bf(v1.w);
  ((u16x8*)Xbf)[i] = o;
}

// ---- prep: build WT[g][k] bf16, g = q*512 + j, k<512 from Wq_x[k][j], else Wq_h[k-512][j].
// LDS-transposed so both global read and write are coalesced.
__global__ __launch_bounds__(256) void build_wt_kernel(
    const float* __restrict__ Wax, const float* __restrict__ Wix,
    const float* __restrict__ Wfx, const float* __restrict__ Wox,
    const float* __restrict__ Wah, const float* __restrict__ Wih,
    const float* __restrict__ Wfh, const float* __restrict__ Woh,
    unsigned short* __restrict__ WT) {
  __shared__ float tile[64][65];
  int bid = blockIdx.x;           // q*128 + jt*16 + kt
  int q  = bid >> 7;
  int jt = (bid >> 4) & 7;
  int kt = bid & 15;
  const float* Wx[4] = {Wax, Wix, Wfx, Wox};
  const float* Wh[4] = {Wah, Wih, Wfh, Woh};
  const float* src = (kt < 8) ? Wx[q] : Wh[q];
  int k0 = (kt & 7) * 64;
  int j0 = jt * 64;
  int tid = threadIdx.x;
#pragma unroll
  for (int e = 0; e < 16; ++e) {
    int lin = e * 256 + tid;
    int kk = lin >> 6, jj = lin & 63;
    tile[kk][jj] = src[(size_t)(k0 + kk) * HH + j0 + jj];
  }
  __syncthreads();
#pragma unroll
  for (int e = 0; e < 16; ++e) {
    int lin = e * 256 + tid;
    int jj = lin >> 6, kk = lin & 63;
    WT[(size_t)(q * HH + j0 + jj) * KK + kt * 64 + kk] = f2bf(tile[kk][jj]);
  }
}

// ---- main persistent recurrence kernel ----
__global__ __launch_bounds__(256) void lstm_main(
    const unsigned short* __restrict__ Xbf,
    const unsigned short* __restrict__ WT,
    const float* __restrict__ ba, const float* __restrict__ bi,
    const float* __restrict__ bfg, const float* __restrict__ bo,
    unsigned short* __restrict__ hbuf,
    float* __restrict__ out,
    int* __restrict__ flags) {
  const int tid  = threadIdx.x;
  const int bid  = blockIdx.x;
  const int lane = tid & 63;
  const int wave = tid >> 6;
  const int rb = bid >> 4;           // 0..3  (32 batch rows each)
  const int cb = bid & 15;           // 0..15 (32 hidden each)
  const int rt = wave >> 1;          // 0..1
  const int ch = wave & 1;           // 0..1
  const int l15 = lane & 15;
  const int lk  = (lane >> 4) * 8;   // k offset within 32-chunk (A/B frag layout)
  const int rbase = rb * 32 + rt * 16;
  const int jme = cb * 32 + ch * 16 + l15;   // hidden index (B col / C col)

  const unsigned short* wp0 = WT + (size_t)(0 * HH + jme) * KK + lk;
  const unsigned short* wp1 = WT + (size_t)(1 * HH + jme) * KK + lk;
  const unsigned short* wp2 = WT + (size_t)(2 * HH + jme) * KK + lk;
  const unsigned short* wp3 = WT + (size_t)(3 * HH + jme) * KK + lk;

  const float bias0 = ba[jme], bias1 = bi[jme], bias2 = bfg[jme], bias3 = bo[jme];

  const unsigned short* xbase = Xbf + (size_t)(rbase + l15) * DD + lk;
  const size_t hrow_off = (size_t)(rbase + l15) * HH + lk;
  const int crow0 = rbase + (lane >> 4) * 4;

  float s0 = 0.f, s1 = 0.f, s2 = 0.f, s3 = 0.f;

  for (int t = 0; t < TT; ++t) {
    const unsigned short* xt = xbase + (size_t)t * BB * DD;
    const unsigned short* hp = hbuf + (size_t)((t & 1) ^ 1) * BB * HH + hrow_off;

    f32x4 acc0 = {0.f, 0.f, 0.f, 0.f};
    f32x4 acc1 = {0.f, 0.f, 0.f, 0.f};
    f32x4 acc2 = {0.f, 0.f, 0.f, 0.f};
    f32x4 acc3 = {0.f, 0.f, 0.f, 0.f};

#pragma unroll
    for (int kk = 0; kk < 16; ++kk) {   // x part: k in [0,512)
      bf16x8 a = *(const bf16x8*)(xt + kk * 32);
      acc0 = __builtin_amdgcn_mfma_f32_16x16x32_bf16(a, *(const bf16x8*)(wp0 + kk * 32), acc0, 0, 0, 0);
      acc1 = __builtin_amdgcn_mfma_f32_16x16x32_bf16(a, *(const bf16x8*)(wp1 + kk * 32), acc1, 0, 0, 0);
      acc2 = __builtin_amdgcn_mfma_f32_16x16x32_bf16(a, *(const bf16x8*)(wp2 + kk * 32), acc2, 0, 0, 0);
      acc3 = __builtin_amdgcn_mfma_f32_16x16x32_bf16(a, *(const bf16x8*)(wp3 + kk * 32), acc3, 0, 0, 0);
    }
#pragma unroll
    for (int kk = 0; kk < 16; ++kk) {   // h part: k in [512,1024)
      bf16x8 a = *(const bf16x8*)(hp + kk * 32);
      acc0 = __builtin_amdgcn_mfma_f32_16x16x32_bf16(a, *(const bf16x8*)(wp0 + DD + kk * 32), acc0, 0, 0, 0);
      acc1 = __builtin_amdgcn_mfma_f32_16x16x32_bf16(a, *(const bf16x8*)(wp1 + DD + kk * 32), acc1, 0, 0, 0);
      acc2 = __builtin_amdgcn_mfma_f32_16x16x32_bf16(a, *(const bf16x8*)(wp2 + DD + kk * 32), acc2, 0, 0, 0);
      acc3 = __builtin_amdgcn_mfma_f32_16x16x32_bf16(a, *(const bf16x8*)(wp3 + DD + kk * 32), acc3, 0, 0, 0);
    }

    float* op = out + (size_t)t * BB * HH;
    unsigned short* hw = hbuf + (size_t)(t & 1) * BB * HH;

#pragma unroll
    for (int r = 0; r < 4; ++r) {
      float g0 = acc0[r] + bias0;
      float g1 = acc1[r] + bias1;
      float g2 = acc2[r] + bias2;
      float g3 = acc3[r] + bias3;
      float av = ftanh(g0);
      float iv = fsig(g1);
      float fv = fsig(g2);
      float ov = fsig(g3);
      float sp = (r == 0) ? s0 : (r == 1) ? s1 : (r == 2) ? s2 : s3;
      float sn = av * iv + sp * fv;
      if (r == 0) s0 = sn; else if (r == 1) s1 = sn; else if (r == 2) s2 = sn; else s3 = sn;
      float hv = ftanh(sn) * ov;
      int crow = crow0 + r;
      op[(size_t)crow * HH + jme] = hv;
      hw[(size_t)crow * HH + jme] = f2bf(hv);
    }

    if (t == TT - 1) break;

    // ---- grid barrier: publish h_t, wait for all blocks ----
    __syncthreads();
    if (wave == 0) {
      if (lane == 0) {
        __threadfence();  // flush this CU's stores past non-coherent L2
        __hip_atomic_store(&flags[bid * 16], t + 1, __ATOMIC_RELEASE, __HIP_MEMORY_SCOPE_AGENT);
      }
      int v;
      do {
        v = __hip_atomic_load(&flags[lane * 16], __ATOMIC_ACQUIRE, __HIP_MEMORY_SCOPE_AGENT);
      } while (__any(v <= t));
    }
    __syncthreads();
    __threadfence();  // invalidate L1/L2 so fresh h is visible to every wave
  }
}

extern "C" void kernel_launch(void* const* d_in, const int* in_sizes, int n_in,
                              void* d_out, int out_size, void* d_ws, size_t ws_size,
                              hipStream_t stream) {
  const float* X   = (const float*)d_in[0];
  const float* Wax = (const float*)d_in[1];
  const float* Wix = (const float*)d_in[2];
  const float* Wfx = (const float*)d_in[3];
  const float* Wox = (const float*)d_in[4];
  const float* Wah = (const float*)d_in[5];
  const float* Wih = (const float*)d_in[6];
  const float* Wfh = (const float*)d_in[7];
  const float* Woh = (const float*)d_in[8];
  const float* ba  = (const float*)d_in[9];
  const float* bi  = (const float*)d_in[10];
  const float* bf  = (const float*)d_in[11];
  const float* bo  = (const float*)d_in[12];
  float* out = (float*)d_out;

  char* ws = (char*)d_ws;
  unsigned short* Xbf  = (unsigned short*)ws;                               // 33,554,432 B
  unsigned short* WT   = (unsigned short*)(ws + 33554432);                  //  4,194,304 B
  unsigned short* hbuf = (unsigned short*)(ws + 33554432 + 4194304);        //    262,144 B
  int* flags           = (int*)(ws + 33554432 + 4194304 + 262144);          //      4,096 B

  // zero h_{-1} and barrier flags every launch (ws is poisoned / stale across replays)
  hipMemsetAsync(hbuf, 0, 262144 + 4096, stream);

  convert_x_kernel<<<8192, 256, 0, stream>>>(X, Xbf);
  build_wt_kernel<<<512, 256, 0, stream>>>(Wax, Wix, Wfx, Wox, Wah, Wih, Wfh, Woh, WT);
  lstm_main<<<NBLK, 256, 0, stream>>>(Xbf, WT, ba, bi, bf, bo, hbuf, out, flags);
}